// Round 4
// baseline (652.956 us; speedup 1.0000x reference)
//
#include <hip/hip_runtime.h>

#define D 64
#define KCODES 1024
#define KHALF 512
#define RSTRIDE 68  // padded row: 64 code floats + en2 + 3 pad = 272 B (16B-aligned)

// Prep: embedT2[k][0..63] = e_k (transposed codebook), [64] = ||e_k||^2, [65..67] = 0.
// Same fma order for en2 as R1-R3 (numerics must stay identical).
// Also zeroes the divergence-poison buffer (ws is re-poisoned 0xAA before every launch).
__global__ void __launch_bounds__(256) vq_prep_kernel(const float* __restrict__ embed,
                                                      float* __restrict__ embedT2,
                                                      int* __restrict__ zero_buf) {
  int k = blockIdx.x * blockDim.x + threadIdx.x;
  if (k < 256) zero_buf[k] = 0;
  if (k >= KCODES) return;
  float s = 0.f;
  float* row = embedT2 + (size_t)k * RSTRIDE;
#pragma unroll
  for (int d = 0; d < D; ++d) {
    float e = embed[d * KCODES + k];
    row[d] = e;
    s = fmaf(e, e, s);
  }
  row[64] = s;
  row[65] = 0.f; row[66] = 0.f; row[67] = 0.f;
}

// Block = 256 threads / 256 points. Threads 0..127 scan codes [0,512), threads
// 128..255 scan [512,1024); each thread owns points (th, th+128). Code rows are
// read with uniform-address VECTOR loads (global_load_dwordx4): the address is
// poisoned with z (=0, loaded from memory, unprovable) so the compiler cannot
// convert back to s_load. Unlike SMEM (out-of-order, lgkmcnt(0) drain), VMEM
// drains in-order via vmcnt(N) -> the loads pipeline across iterations.
__global__ void __launch_bounds__(256, 2) vq_main_kernel(
    const float* __restrict__ inputs, const float* __restrict__ embedT2,
    const int* __restrict__ zero_buf, float* __restrict__ out_q,
    float* __restrict__ out_codes, float* __restrict__ out_idx) {
  __shared__ float s_best[256];
  __shared__ int   s_idx[256];
  __shared__ int   s_fin[256];

  const int t  = threadIdx.x;
  const int th = t & 127;
  const int base = blockIdx.x * 256;
  const int p0 = base + th;
  const int p1 = base + th + 128;

  const int z  = zero_buf[t];  // == 0, but divergent as far as the compiler knows
  const int k0 = (t >= 128) ? KHALF : 0;
  const float* __restrict__ erow = embedT2 + (size_t)(k0 + z) * RSTRIDE;

  // Two point vectors in VGPRs (coalesced float4 loads).
  float f0[D], f1[D];
  {
    const float4* i40 = reinterpret_cast<const float4*>(inputs + (size_t)p0 * D);
    const float4* i41 = reinterpret_cast<const float4*>(inputs + (size_t)p1 * D);
#pragma unroll
    for (int d4 = 0; d4 < D / 4; ++d4) {
      float4 a = i40[d4];
      float4 b = i41[d4];
      f0[4 * d4 + 0] = a.x; f0[4 * d4 + 1] = a.y; f0[4 * d4 + 2] = a.z; f0[4 * d4 + 3] = a.w;
      f1[4 * d4 + 0] = b.x; f1[4 * d4 + 1] = b.y; f1[4 * d4 + 2] = b.z; f1[4 * d4 + 3] = b.w;
    }
  }
  float fn20 = 0.f, fn21 = 0.f;
#pragma unroll
  for (int d = 0; d < D; ++d) fn20 = fmaf(f0[d], f0[d], fn20);
#pragma unroll
  for (int d = 0; d < D; ++d) fn21 = fmaf(f1[d], f1[d], fn21);

  float best0 = 3.4e38f, best1 = 3.4e38f;
  int bi0 = k0, bi1 = k0;

#pragma unroll 1
  for (int kk = 0; kk < KHALF; ++kk) {
    const float4* __restrict__ e4 =
        reinterpret_cast<const float4*>(erow + (size_t)kk * RSTRIDE);
    // 17 x global_load_dwordx4, uniform address (1 cacheline request each,
    // HW-broadcast to lanes). Loaded into VGPRs up front so vmcnt pipelines.
    float4 r[16];
#pragma unroll
    for (int i = 0; i < 16; ++i) r[i] = e4[i];
    float4 tail = e4[16];  // .x = en2[k]
    float a0 = 0.f, a1 = 0.f, a2 = 0.f, a3 = 0.f;  // same 4-chain split as R2/R3
    float b0 = 0.f, b1 = 0.f, b2 = 0.f, b3 = 0.f;
#pragma unroll
    for (int i = 0; i < 16; ++i) {
      int d = 4 * i;
      a0 = fmaf(f0[d + 0], r[i].x, a0);
      a1 = fmaf(f0[d + 1], r[i].y, a1);
      a2 = fmaf(f0[d + 2], r[i].z, a2);
      a3 = fmaf(f0[d + 3], r[i].w, a3);
      b0 = fmaf(f1[d + 0], r[i].x, b0);
      b1 = fmaf(f1[d + 1], r[i].y, b1);
      b2 = fmaf(f1[d + 2], r[i].z, b2);
      b3 = fmaf(f1[d + 3], r[i].w, b3);
    }
    float dot0 = (a0 + a1) + (a2 + a3);
    float dot1 = (b0 + b1) + (b2 + b3);
    float en = tail.x;
    float d0 = fmaf(-2.f, dot0, fn20) + en;  // same rounding order as R2/R3
    float d1 = fmaf(-2.f, dot1, fn21) + en;
    int k = k0 + kk;
    if (d0 < best0) { best0 = d0; bi0 = k; }  // strict < = first occurrence
    if (d1 < best1) { best1 = d1; bi1 = k; }
  }

  // Merge the two K-halves; strict < favoring the low half = first-occurrence.
  if (t >= 128) {
    s_best[th] = best0;       s_idx[th] = bi0;
    s_best[th + 128] = best1; s_idx[th + 128] = bi1;
  }
  __syncthreads();
  if (t < 128) {
    if (s_best[th] < best0) bi0 = s_idx[th];
    if (s_best[th + 128] < best1) bi1 = s_idx[th + 128];
    s_fin[th] = bi0;
    s_fin[th + 128] = bi1;
  }
  __syncthreads();

  // Split epilogue; winner rows are L2-resident (embedT2 = 272 KB).
  if (t < 128) {
    const float4* q0 = reinterpret_cast<const float4*>(embedT2 + (size_t)bi0 * RSTRIDE);
    const float4* q1 = reinterpret_cast<const float4*>(embedT2 + (size_t)bi1 * RSTRIDE);
    float4* o0 = reinterpret_cast<float4*>(out_q + (size_t)p0 * D);
    float4* o1 = reinterpret_cast<float4*>(out_q + (size_t)p1 * D);
#pragma unroll
    for (int d4 = 0; d4 < D / 4; ++d4) { o0[d4] = q0[d4]; o1[d4] = q1[d4]; }
    out_idx[p0] = (float)bi0;
    out_idx[p1] = (float)bi1;
  } else {
    int fi0 = s_fin[th], fi1 = s_fin[th + 128];
    const float4* q0 = reinterpret_cast<const float4*>(embedT2 + (size_t)fi0 * RSTRIDE);
    const float4* q1 = reinterpret_cast<const float4*>(embedT2 + (size_t)fi1 * RSTRIDE);
    float4* c0 = reinterpret_cast<float4*>(out_codes + (size_t)p0 * 2 * D);
    float4* c1 = reinterpret_cast<float4*>(out_codes + (size_t)p1 * 2 * D);
#pragma unroll
    for (int d4 = 0; d4 < D / 4; ++d4) {
      c0[d4] = make_float4(f0[4 * d4], f0[4 * d4 + 1], f0[4 * d4 + 2], f0[4 * d4 + 3]);
      c1[d4] = make_float4(f1[4 * d4], f1[4 * d4 + 1], f1[4 * d4 + 2], f1[4 * d4 + 3]);
      c0[D / 4 + d4] = q0[d4];
      c1[D / 4 + d4] = q1[d4];
    }
  }
}

extern "C" void kernel_launch(void* const* d_in, const int* in_sizes, int n_in,
                              void* d_out, int out_size, void* d_ws, size_t ws_size,
                              hipStream_t stream) {
  const float* inputs = (const float*)d_in[0];
  const float* embed  = (const float*)d_in[1];
  int N = in_sizes[0] / D;  // 131072

  float* embedT2 = (float*)d_ws;                   // 1024*68 floats = 272 KB
  int*   zero_buf = (int*)(embedT2 + KCODES * RSTRIDE);  // 256 ints
  float* out = (float*)d_out;
  float* out_q     = out;                      // [N, 64]
  float* out_codes = out + (size_t)N * D;      // [N, 128]
  float* out_idx   = out + (size_t)N * D * 3;  // [N]

  vq_prep_kernel<<<(KCODES + 255) / 256, 256, 0, stream>>>(embed, embedT2, zero_buf);
  vq_main_kernel<<<N / 256, 256, 0, stream>>>(inputs, embedT2, zero_buf,
                                              out_q, out_codes, out_idx);
}

// Round 5
// 309.986 us; speedup vs baseline: 2.1064x; 2.1064x over previous
//
#include <hip/hip_runtime.h>

#define D 64
#define KCODES 1024
#define PTS_PER_BLK 256
#define MTILES 16       // 16 points per M-tile
#define NT 16           // N-tiles (of 16 codes) per wave -> 256 codes/wave, 1024/block
#define WL_CAP 8192

typedef short bf16x8 __attribute__((ext_vector_type(8)));
typedef float f32x4 __attribute__((ext_vector_type(4)));

static __device__ __forceinline__ short f2bf(float f) {  // RNE fp32->bf16
  unsigned u = __float_as_uint(f);
  u += 0x7FFF + ((u >> 16) & 1);
  return (short)(u >> 16);
}

// Exact fp32 distance, bit-identical to the R1-R4 formula (4-chain fma, then
// fma(-2,dot,fn2)+en2). Packed-key atomicMin: ties -> smaller idx = first occurrence.
static __device__ __forceinline__ void evalExact(const float* __restrict__ inputs,
                                                 const float* __restrict__ embedT,
                                                 const float* __restrict__ en2,
                                                 const float* __restrict__ fn2,
                                                 int p0blk, int pl, int c,
                                                 unsigned long long* s_best) {
  int p = p0blk + pl;
  const float* f = inputs + (size_t)p * D;
  const float* e = embedT + (size_t)c * D;
  float a0 = 0.f, a1 = 0.f, a2 = 0.f, a3 = 0.f;
#pragma unroll
  for (int d = 0; d < D; d += 4) {
    a0 = fmaf(f[d + 0], e[d + 0], a0);
    a1 = fmaf(f[d + 1], e[d + 1], a1);
    a2 = fmaf(f[d + 2], e[d + 2], a2);
    a3 = fmaf(f[d + 3], e[d + 3], a3);
  }
  float dot = (a0 + a1) + (a2 + a3);
  float dist = fmaf(-2.f, dot, fn2[p]) + en2[c];
  unsigned long long key = ((unsigned long long)__float_as_uint(dist) << 32) | (unsigned)c;
  atomicMin(&s_best[pl], key);
}

// K0a: embed [64][1024] -> embedT fp32 [1024][64], embedTb bf16 [1024][64],
// en2[k] (sequential-fma order, identical to R1-R4), en2max (atomicMax on bits;
// ws poison 0xAA... is a negative int, so any positive value wins).
__global__ void __launch_bounds__(256) vq_prep_codes(const float* __restrict__ embed,
                                                     float* __restrict__ embedT,
                                                     unsigned short* __restrict__ embedTb,
                                                     float* __restrict__ en2,
                                                     int* __restrict__ en2max_bits) {
  int k = blockIdx.x * 256 + threadIdx.x;
  float row[D];
  float s = 0.f;
#pragma unroll
  for (int d = 0; d < D; ++d) {
    float e = embed[d * KCODES + k];   // coalesced along k
    row[d] = e;
    s = fmaf(e, e, s);
  }
  en2[k] = s;
  float4* o4 = reinterpret_cast<float4*>(embedT + (size_t)k * D);
#pragma unroll
  for (int j = 0; j < 16; ++j)
    o4[j] = make_float4(row[4 * j], row[4 * j + 1], row[4 * j + 2], row[4 * j + 3]);
  unsigned us[32];
#pragma unroll
  for (int j = 0; j < 32; ++j) {
    unsigned lo = (unsigned short)f2bf(row[2 * j]);
    unsigned hi = (unsigned short)f2bf(row[2 * j + 1]);
    us[j] = lo | (hi << 16);
  }
  uint4* ob = reinterpret_cast<uint4*>(embedTb + (size_t)k * D);
#pragma unroll
  for (int j = 0; j < 8; ++j) ob[j] = make_uint4(us[4 * j], us[4 * j + 1], us[4 * j + 2], us[4 * j + 3]);
  float m = s;
#pragma unroll
  for (int off = 32; off; off >>= 1) m = fmaxf(m, __shfl_down(m, off, 64));
  if ((threadIdx.x & 63) == 0) atomicMax(en2max_bits, __float_as_int(m));
}

// K0b: fn2[p] = ||f_p||^2, sequential-fma order identical to R1-R4.
__global__ void __launch_bounds__(256) vq_prep_fn2(const float* __restrict__ inputs,
                                                   float* __restrict__ fn2) {
  int p = blockIdx.x * 256 + threadIdx.x;
  const float4* i4 = reinterpret_cast<const float4*>(inputs + (size_t)p * D);
  float s = 0.f;
#pragma unroll
  for (int j = 0; j < 16; ++j) {
    float4 v = i4[j];
    s = fmaf(v.x, v.x, s); s = fmaf(v.y, v.y, s);
    s = fmaf(v.z, v.z, s); s = fmaf(v.w, v.w, s);
  }
  fn2[p] = s;
}

// K1: per block: 256 points x all 1024 codes. Each wave holds its 256 codes' B
// fragments in 128 VGPRs for the whole kernel. Per M-tile (16 points): 2 A-frag
// global loads feed 32 MFMAs; epilogue screens d~ against min~+margin; candidates
// -> LDS worklist -> exact fp32 re-eval -> packed atomicMin -> fused outputs.
__global__ void __launch_bounds__(256, 2) vq_main_kernel(
    const float* __restrict__ inputs, const float* __restrict__ embedT,
    const unsigned short* __restrict__ embedTb, const float* __restrict__ en2,
    const float* __restrict__ fn2, const int* __restrict__ en2max_bits,
    float* __restrict__ out_q, float* __restrict__ out_codes,
    float* __restrict__ out_idx) {
  __shared__ unsigned long long s_best[PTS_PER_BLK];
  __shared__ unsigned s_wl[WL_CAP];
  __shared__ int s_wcount;
  __shared__ float s_wmin[4][16];

  const int tid = threadIdx.x;
  const int w = tid >> 6;
  const int l = tid & 63;
  const int l15 = l & 15;
  const int lg = l >> 4;                 // quad-group 0..3
  const int p0blk = blockIdx.x * PTS_PER_BLK;
  const int cbase = w * 256;

  s_best[tid] = ~0ull;
  if (tid == 0) s_wcount = 0;

  const float en2max = __int_as_float(*en2max_bits);

  // B fragments: B[k][n], lane holds n = cbase+16t+l15, k = kf*32 + lg*8 + j.
  // embedTb row n is contiguous in k -> one 16B load per frag.
  bf16x8 bfr[NT][2];
#pragma unroll
  for (int t = 0; t < NT; ++t) {
    const bf16x8* bp = reinterpret_cast<const bf16x8*>(
        embedTb + (size_t)(cbase + 16 * t + l15) * D + lg * 8);
    bfr[t][0] = bp[0];   // k in [lg*8, lg*8+8)
    bfr[t][1] = bp[4];   // +32 shorts -> k in [32+lg*8, ...)
  }
  float en2v[NT];
#pragma unroll
  for (int t = 0; t < NT; ++t) en2v[t] = en2[cbase + 16 * t + l15];

  __syncthreads();

#pragma unroll 1
  for (int mt = 0; mt < MTILES; ++mt) {
    const int p0 = p0blk + mt * 16;
    // A fragment: lane holds m = p0+l15, k = kf*32 + lg*8 + j (fp32->bf16 inline).
    const float* arow = inputs + (size_t)(p0 + l15) * D + lg * 8;
    f32x4 acc[NT];
#pragma unroll
    for (int t = 0; t < NT; ++t) acc[t] = (f32x4){0.f, 0.f, 0.f, 0.f};
#pragma unroll
    for (int kf = 0; kf < 2; ++kf) {
      float4 a0 = *reinterpret_cast<const float4*>(arow + kf * 32);
      float4 a1 = *reinterpret_cast<const float4*>(arow + kf * 32 + 4);
      bf16x8 af;
      af[0] = f2bf(a0.x); af[1] = f2bf(a0.y); af[2] = f2bf(a0.z); af[3] = f2bf(a0.w);
      af[4] = f2bf(a1.x); af[5] = f2bf(a1.y); af[6] = f2bf(a1.z); af[7] = f2bf(a1.w);
#pragma unroll
      for (int t = 0; t < NT; ++t)
        acc[t] = __builtin_amdgcn_mfma_f32_16x16x32_bf16(af, bfr[t][kf], acc[t], 0, 0, 0);
    }
    // C/D layout: row(point) = lg*4 + reg, col(code) = l15 [m89/m91-verified].
    float fnv[4];
#pragma unroll
    for (int r = 0; r < 4; ++r) fnv[r] = fn2[p0 + lg * 4 + r];
#pragma unroll
    for (int t = 0; t < NT; ++t)
#pragma unroll
      for (int r = 0; r < 4; ++r)
        acc[t][r] = fmaf(-2.f, acc[t][r], fnv[r]) + en2v[t];

    // min~ per point: lane-local over t, butterfly over the 16 cols, LDS over waves.
    float m[4];
#pragma unroll
    for (int r = 0; r < 4; ++r) {
      float mm = acc[0][r];
#pragma unroll
      for (int t = 1; t < NT; ++t) mm = fminf(mm, acc[t][r]);
#pragma unroll
      for (int s = 1; s < 16; s <<= 1) mm = fminf(mm, __shfl_xor(mm, s, 16));
      m[r] = mm;
    }
    if (l15 == 0) {
#pragma unroll
      for (int r = 0; r < 4; ++r) s_wmin[w][lg * 4 + r] = m[r];
    }
    __syncthreads();
    float thr[4];
#pragma unroll
    for (int r = 0; r < 4; ++r) {
      int q = lg * 4 + r;
      float fm = fminf(fminf(s_wmin[0][q], s_wmin[1][q]), fminf(s_wmin[2][q], s_wmin[3][q]));
      // margin >= 2*|d~ - d| bound: bf16 u=2^-8 -> 2*2^-7*sqrt(fn2*en2) + accum slack, x2 safety.
      thr[r] = fm + (0.03125f * sqrtf(fnv[r] * en2max) + 0.01f);
    }
#pragma unroll
    for (int t = 0; t < NT; ++t)
#pragma unroll
      for (int r = 0; r < 4; ++r)
        if (acc[t][r] <= thr[r]) {
          int pl = mt * 16 + lg * 4 + r;
          int c = cbase + 16 * t + l15;
          int pos = atomicAdd(&s_wcount, 1);
          if (pos < WL_CAP) s_wl[pos] = (unsigned)((pl << 10) | c);
          else evalExact(inputs, embedT, en2, fn2, p0blk, pl, c, s_best);  // overflow fallback
        }
    __syncthreads();  // s_wmin reused next M-tile
  }

  // Exact re-eval of the worklist (parallel across the block).
  int wc = s_wcount; if (wc > WL_CAP) wc = WL_CAP;
  for (int i = tid; i < wc; i += 256)
    evalExact(inputs, embedT, en2, fn2, p0blk, (int)(s_wl[i] >> 10), (int)(s_wl[i] & 1023), s_best);
  __syncthreads();

  // Outputs: 4 lanes cooperate per point; lanes 0-3 cover 64B-contiguous chunks.
  const int sub = tid & 3;
#pragma unroll 1
  for (int pass = 0; pass < 4; ++pass) {
    int pl = pass * 64 + (tid >> 2);
    unsigned long long key = s_best[pl];
    int c = (int)(unsigned)(key & 0xFFFFFFFFu);
    int p = p0blk + pl;
    const float4* qrow = reinterpret_cast<const float4*>(embedT + (size_t)c * D);
    const float4* frow = reinterpret_cast<const float4*>(inputs + (size_t)p * D);
    float4* oq = reinterpret_cast<float4*>(out_q + (size_t)p * D);
    float4* oc = reinterpret_cast<float4*>(out_codes + (size_t)p * 2 * D);
#pragma unroll
    for (int j = 0; j < 4; ++j) {
      int i4 = j * 4 + sub;
      float4 qv = qrow[i4];
      float4 fv = frow[i4];
      oq[i4] = qv;
      oc[i4] = fv;
      oc[16 + i4] = qv;
    }
    if (sub == 0) out_idx[p] = (float)c;
  }
}

extern "C" void kernel_launch(void* const* d_in, const int* in_sizes, int n_in,
                              void* d_out, int out_size, void* d_ws, size_t ws_size,
                              hipStream_t stream) {
  const float* inputs = (const float*)d_in[0];
  const float* embed  = (const float*)d_in[1];
  int N = in_sizes[0] / D;  // 131072

  float* embedT          = (float*)d_ws;                         // 256 KB
  unsigned short* embedTb = (unsigned short*)(embedT + KCODES * D);  // 128 KB
  float* en2             = (float*)(embedTb + KCODES * D);       // 4 KB
  float* fn2             = en2 + KCODES;                         // 512 KB
  int* en2max_bits       = (int*)(fn2 + N);                      // 4 B

  float* out = (float*)d_out;
  float* out_q     = out;                      // [N, 64]
  float* out_codes = out + (size_t)N * D;      // [N, 128]
  float* out_idx   = out + (size_t)N * D * 3;  // [N]

  vq_prep_codes<<<KCODES / 256, 256, 0, stream>>>(embed, embedT, embedTb, en2, en2max_bits);
  vq_prep_fn2<<<N / 256, 256, 0, stream>>>(inputs, fn2);
  vq_main_kernel<<<N / PTS_PER_BLK, 256, 0, stream>>>(inputs, embedT, embedTb, en2, fn2,
                                                      en2max_bits, out_q, out_codes, out_idx);
}